// Round 13
// baseline (153.536 us; speedup 1.0000x reference)
//
#include <hip/hip_runtime.h>
#include <hip/hip_bf16.h>

// ---------------------------------------------------------------------------
// Attention (B=2,N=2048,D=1024,H=16,DH=64) on gfx950 — full-fp16 pipeline.
//   1. prep: x -> fp16; Wq|Wk|Wv|Wo -> W^T fp16; compact rope tables
//      RC2/RS2 [2048][64] f32 (L2-resident).
//   2. gemm<128,0>: q|k|v = x@W+b in ONE gemm (bijective XCD swizzle);
//      epilogue: rope (+log2e on q) -> QK fp16; v -> VT [B,H,64,N] fp16.
//   3. attn: flash attn, 32x32x16 MFMA, 4-way key split, 4-wave blocks,
//      2048 blocks, 64-key super-tiles (2x32 chunks per barrier).
//      ROUND-13: critical-path reorder — exp2 in place IMMEDIATELY after
//      QK (C-init = -mrun makes the common path subtraction-free); max
//      tree + vote run concurrently; rare fixup rescales p by 2^-delta;
//      row-sum via depth-4 f32 tree (was 8-deep fdot chain).
//      launch_bounds (256,4) — (256,8) caused the round-9 spill regression.
//      Writes NORMALIZED partials (o/l as packed fp16) + (m,l) per row.
//   4. combine: weighted-merge 4 segments -> ctx fp16.
//   5. gemm<64,2>: out = (ctx@Wo + bo) * query_mask, f32.
// ---------------------------------------------------------------------------

typedef __fp16 fp16x2 __attribute__((ext_vector_type(2)));
typedef _Float16 f16x8 __attribute__((ext_vector_type(8)));
typedef float f32x4 __attribute__((ext_vector_type(4)));
typedef float f32x16 __attribute__((ext_vector_type(16)));

#define NEGBIG (-1.0e9f)

__device__ inline f32x4 mfma16(f16x8 a, f16x8 b, f32x4 c) {
  return __builtin_amdgcn_mfma_f32_16x16x32_f16(a, b, c, 0, 0, 0);
}
__device__ inline f32x16 mfma32(f16x8 a, f16x8 b, f32x16 c) {
  return __builtin_amdgcn_mfma_f32_32x32x16_f16(a, b, c, 0, 0, 0);
}

__device__ inline void gload16(const void* g, void* l) {
  __builtin_amdgcn_global_load_lds(
      (const __attribute__((address_space(1))) void*)g,
      (__attribute__((address_space(3))) void*)l, 16, 0, 0);
}

__device__ inline unsigned pk2u(float a, float b) {
  union { fp16x2 h; unsigned u; } x;
  x.h = __builtin_amdgcn_cvt_pkrtz(a, b);
  return x.u;
}

__device__ inline float max3f(float a, float b, float c) {
  float d;
  asm("v_max3_f32 %0, %1, %2, %3" : "=v"(d) : "v"(a), "v"(b), "v"(c));
  return d;
}

// -------------------------------- prep -------------------------------------
// z<4: W[z] transpose -> fp16. z==4: x -> fp16. z==5: compact rope tables.
__global__ __launch_bounds__(256) void prep_kernel(
    const float* __restrict__ x, const float* __restrict__ Wq,
    const float* __restrict__ Wk, const float* __restrict__ Wv,
    const float* __restrict__ Wo, const float* __restrict__ rc,
    const float* __restrict__ rs, _Float16* __restrict__ xh,
    _Float16* __restrict__ wt, float* __restrict__ rc2,
    float* __restrict__ rs2) {
  __shared__ float tile[32][33];
  const int z = blockIdx.z;
  const int tx = threadIdx.x, ty = threadIdx.y;
  if (z == 4) {
    const int bid = blockIdx.y * 32 + blockIdx.x;
    const int t = ty * 32 + tx;
#pragma unroll
    for (int i = 0; i < 4; ++i) {
      const int o = bid * 1024 + i * 256 + t;
      const float4 v = ((const float4*)x)[o];
      union { _Float16 h[4]; short4 s; } u;
      u.h[0] = (_Float16)v.x; u.h[1] = (_Float16)v.y;
      u.h[2] = (_Float16)v.z; u.h[3] = (_Float16)v.w;
      ((short4*)xh)[o] = u.s;
    }
    return;
  }
  if (z == 5) {
    const int bid = blockIdx.y * 32 + blockIdx.x;
    const int idx = bid * 256 + ty * 32 + tx;  // over 2048*64 = 131072
    if (idx < 131072) {
      const int n = idx >> 6, d = idx & 63;
      rc2[idx] = rc[(size_t)n * 1024 + d];
      rs2[idx] = rs[(size_t)n * 1024 + d];
    }
    return;
  }
  const float* W = (z == 0) ? Wq : (z == 1) ? Wk : (z == 2) ? Wv : Wo;
  _Float16* dh = wt + (size_t)z * 1024 * 1024;
  const int j0 = blockIdx.x * 32, k0 = blockIdx.y * 32;
  for (int i = ty; i < 32; i += 8)
    tile[i][tx] = W[(size_t)(k0 + i) * 1024 + j0 + tx];
  __syncthreads();
  for (int i = ty; i < 32; i += 8)
    dh[(size_t)(j0 + i) * 1024 + k0 + tx] = (_Float16)tile[tx][i];
}

// -------------------------------- GEMM -------------------------------------
// 1-D grid, bijective XCD swizzle (nwg % 8 == 0). M = 4096 fixed.
template <int TM, int EPI>
__global__ __launch_bounds__(256) void gemm_kernel(
    const _Float16* __restrict__ A, const _Float16* __restrict__ B,
    const float* __restrict__ bias0, const float* __restrict__ bias1,
    const float* __restrict__ bias2,
    const float* __restrict__ ropeC, const float* __restrict__ ropeS,
    const int* __restrict__ lens,
    _Float16* __restrict__ outQK, _Float16* __restrict__ outVT,
    float* __restrict__ outF) {
  constexpr int MI = TM / 32;
  constexpr int MSHIFT = (TM == 128) ? 5 : 6;  // mtiles = 4096/TM
  __shared__ __align__(16) _Float16 smem[(TM + 128) * 32];
  const int t = threadIdx.x;
  const int w = t >> 6, lane = t & 63;
  const int wr = w >> 1, wc = w & 1;
  const int fr = lane & 15, fg = lane >> 4;
  const int nwg = gridDim.x;
  const int bid = blockIdx.x;
  const int wgid = (bid & 7) * (nwg >> 3) + (bid >> 3);
  const int mtile = wgid & ((1 << MSHIFT) - 1);
  const int ntile = wgid >> MSHIFT;

  const int srow = t >> 2;
  const int skel = (t & 3) << 3;
  const size_t aBase = (size_t)(mtile * TM + srow) * 1024 + skel;
  const size_t bBase = (size_t)(ntile * 128 + srow) * 1024 + skel;
  const int ldst = t * 8;
  _Float16* lA = &smem[0];
  _Float16* lB = &smem[TM * 32];

  f32x4 acc[MI][4];
#pragma unroll
  for (int i = 0; i < MI; ++i)
#pragma unroll
    for (int j = 0; j < 4; ++j) {
      acc[i][j][0] = 0.f; acc[i][j][1] = 0.f; acc[i][j][2] = 0.f; acc[i][j][3] = 0.f;
    }

  for (int k0 = 0; k0 < 1024; k0 += 32) {
    gload16(A + aBase + k0, lA + ldst);
    if constexpr (TM == 128) gload16(A + aBase + k0 + 64 * 1024, lA + ldst + 2048);
    gload16(B + bBase + k0, lB + ldst);
    gload16(B + bBase + k0 + 64 * 1024, lB + ldst + 2048);
    __syncthreads();

    f16x8 af[MI], bf[4];
#pragma unroll
    for (int mi = 0; mi < MI; ++mi)
      af[mi] = *(const f16x8*)&lA[(wr * (TM / 2) + mi * 16 + fr) * 32 + fg * 8];
#pragma unroll
    for (int ni = 0; ni < 4; ++ni)
      bf[ni] = *(const f16x8*)&lB[(wc * 64 + ni * 16 + fr) * 32 + fg * 8];
#pragma unroll
    for (int mi = 0; mi < MI; ++mi)
#pragma unroll
      for (int ni = 0; ni < 4; ++ni)
        acc[mi][ni] = mfma16(af[mi], bf[ni], acc[mi][ni]);
    __syncthreads();
  }

  const int rowbase = mtile * TM + wr * (TM / 2);
  const int colbase = ntile * 128 + wc * 64;

  if constexpr (EPI == 0) {
    const int which = colbase >> 10;  // 0=q 1=k 2=v (block-uniform)
    if (which < 2) {
      const float* bias = which ? bias1 : bias0;
#pragma unroll
      for (int ni = 0; ni < 4; ++ni) {
        const int gcol = colbase + ni * 16 + fr;
        const int jj = gcol & 1023;
        const int hh = jj >> 6, dd = jj & 63;
        const float bv = bias[jj];
#pragma unroll
        for (int mi = 0; mi < MI; ++mi) {
#pragma unroll
          for (int r = 0; r < 4; ++r) {
            const int grow = rowbase + mi * 16 + fg * 4 + r;
            const int b = grow >> 11, n = grow & 2047;
            float val = acc[mi][ni][r] + bv;
            float part = __shfl_xor(val, 1);
            const int ro = n * 64 + dd;  // compact table
            const float c = ropeC[ro], s = ropeS[ro];
            float rot = (fr & 1) ? (val * c + part * s) : (val * c - part * s);
            if (!which) rot *= 1.44269504f;  // log2e folded into q
            outQK[((size_t)((which * 2 + b) * 16 + hh) * 2048 + n) * 64 + dd] =
                (_Float16)rot;
          }
        }
      }
    } else {
#pragma unroll
      for (int ni = 0; ni < 4; ++ni) {
        const int gcol = colbase + ni * 16 + fr;
        const int jj = gcol & 1023;
        const int hh = jj >> 6, dd = jj & 63;
        const float bv = bias2[jj];
#pragma unroll
        for (int mi = 0; mi < MI; ++mi) {
          const int n0 = rowbase + mi * 16 + fg * 4;
          const int b = n0 >> 11, n = n0 & 2047;
          union { _Float16 h[4]; short4 s4; } u;
#pragma unroll
          for (int r = 0; r < 4; ++r) u.h[r] = (_Float16)(acc[mi][ni][r] + bv);
          *(short4*)(outVT + ((size_t)(b * 16 + hh) * 64 + dd) * 2048 + n) = u.s4;
        }
      }
    }
  } else {
    const int b = rowbase >> 11;
    const int len = lens[b];
#pragma unroll
    for (int ni = 0; ni < 4; ++ni) {
      const int gcol = colbase + ni * 16 + fr;
      const float bv = bias0[gcol];
#pragma unroll
      for (int mi = 0; mi < MI; ++mi) {
#pragma unroll
        for (int r = 0; r < 4; ++r) {
          const int m = rowbase + mi * 16 + fg * 4 + r;
          const int n = m & 2047;
          float val = acc[mi][ni][r] + bv;
          if (n >= len) val = 0.f;
          outF[(size_t)m * 1024 + gcol] = val;
        }
      }
    }
  }
}

// ------------------------------ attention ----------------------------------
// 2048 blocks x 4 waves, wave = 32 q rows, 4-way key split. Grid: xcd=gid&7,
// idx=gid>>3; qtile=idx&15, c=(idx>>4)*8+xcd; bh=c>>2, seg=c&3.
// 64-key super-tiles per barrier (2x32-key chunks, shared vmcnt/barrier).
// S^T = mfma32(K,Q): col=lane&31=q (lane-local), row=(r&3)+8*(r>>2)+4*hi=key.
// Shifted-domain softmax: C-init = -mrun; exp2 IN PLACE right after QK;
// max tree + vote run concurrently; rare fixup rescales p by 2^-delta.
// LDS: 2 x { K[64][64] 8KB | V 2x4KB } = 32 KiB.
__global__ __launch_bounds__(256, 4) void attn_kernel(
    const _Float16* __restrict__ qk, const _Float16* __restrict__ vt,
    const int* __restrict__ lens, unsigned* __restrict__ po,
    float2* __restrict__ ml) {
  __shared__ __align__(16) char lds[32768];
  const int t = threadIdx.x;
  const int w = t >> 6, lane = t & 63;
  const int lq = lane & 31, hi = lane >> 5;
  const int gid = blockIdx.x;
  const int xcd = gid & 7, idx = gid >> 3;
  const int qtile = idx & 15;
  const int c = ((idx >> 4) << 3) + xcd;  // 0..127, same c -> same XCD
  const int bh = c >> 2, seg = c & 3;
  const int b = bh >> 4, h = bh & 15;
  const int len = lens[b];
  const int q0w = qtile * 128 + w * 32;
  const size_t qoff = (size_t)(b * 16 + h) * 2048 * 64;
  const size_t koff = (size_t)((2 + b) * 16 + h) * 2048 * 64;
  const size_t voff = (size_t)(b * 16 + h) * 64 * 2048;

  // Q B-frags: lane lq = q row, k = ks*16 + hi*8 + j
  f16x8 qf[4];
#pragma unroll
  for (int ks = 0; ks < 4; ++ks)
    qf[ks] = *(const f16x8*)(qk + qoff + (size_t)(q0w + lq) * 64 + ks * 16 + hi * 8);

  // staging (4 issues/thread per 64-key super-tile): linear LDS dest, source
  // pre-swizzled slot ss = (t&7)^(srow&7).
  const int srow = t >> 3;  // 0..31
  const int ss = (t & 7) ^ (srow & 7);
  const size_t kg = koff + (size_t)srow * 64 + ss * 8;
  const int vd = srow + ((ss >> 2) << 5);
  const size_t vg = voff + (size_t)vd * 2048 + (ss & 3) * 8;

  f32x16 o0, o1;
#pragma unroll
  for (int i = 0; i < 16; ++i) { o0[i] = 0.f; o1[i] = 0.f; }
  float mrun = 0.f, lsum = 0.f;  // per-lane, q = lq (replicated on hi pair)

#define STAGE(bi, tile0) do { \
    char* dst = lds + (bi) * 16384 + t * 16; \
    const size_t kk = (size_t)(tile0) * 2048; /* tile0*32*64 */ \
    gload16(qk + kg + kk, dst); \
    gload16(qk + kg + kk + 2048, dst + 4096); \
    gload16(vt + vg + (tile0) * 32, dst + 8192); \
    gload16(vt + vg + (tile0) * 32 + 32, dst + 12288); \
  } while (0)

  const int nkb = (len + 31) >> 5;
  const int tb0 = (nkb * seg) >> 2;
  const int tb1 = (nkb * (seg + 1)) >> 2;
  const int nst = (tb1 - tb0 + 1) >> 1;  // 64-key super-tiles

  STAGE(0, tb0);

  for (int st = 0; st < nst; ++st) {
    const int cur = st & 1;
    if (st + 1 < nst) {
      STAGE(cur ^ 1, tb0 + (st + 1) * 2);
      asm volatile("s_waitcnt vmcnt(4)" ::: "memory");
    } else {
      asm volatile("s_waitcnt vmcnt(0)" ::: "memory");
    }
    __builtin_amdgcn_s_barrier();

    const char* Bb = lds + cur * 16384;
    const int rsw = (lq & 7) << 4;

#pragma unroll
    for (int ch = 0; ch < 2; ++ch) {
      const int kb = tb0 + st * 2 + ch;
      if (kb < tb1) {
        const char* Kb = Bb + ch * 4096;
        const char* Vb = Bb + 8192 + ch * 4096;

        // QK^T in shifted domain: C-init = -mrun
        f32x16 s0;
        const float nm = -mrun;
#pragma unroll
        for (int i = 0; i < 16; ++i) s0[i] = nm;
        __builtin_amdgcn_s_setprio(1);
#pragma unroll
        for (int ks = 0; ks < 4; ++ks) {
          const f16x8 kf =
              *(const f16x8*)(Kb + lq * 128 + ((ks * 32 + hi * 16) ^ rsw));
          s0 = mfma32(kf, qf[ks], s0);
        }
        __builtin_amdgcn_s_setprio(0);

        if (kb == nkb - 1 && (len & 31)) {
#pragma unroll
          for (int r = 0; r < 16; ++r) {
            const int key = kb * 32 + (r & 3) + ((r >> 2) << 3) + hi * 4;
            if (key >= len) s0[r] = NEGBIG;
          }
        }

        // --- max tree (v_max3), q lane-local; overlaps the in-place exp2 ---
        const float m0 = max3f(s0[0], s0[1], s0[2]);
        const float m1 = max3f(s0[3], s0[4], s0[5]);
        const float m2 = max3f(s0[6], s0[7], s0[8]);
        const float m3 = max3f(s0[9], s0[10], s0[11]);
        const float m4 = max3f(s0[12], s0[13], s0[14]);
        float mx = fmaxf(max3f(m0, m1, m2), max3f(m3, m4, s0[15]));
        mx = fmaxf(mx, __shfl_xor(mx, 32));

        // p = exp2(s0) IN PLACE — no wait on the vote (common path needs no
        // subtraction: the -mrun shift is already folded into the C-init)
#pragma unroll
        for (int i = 0; i < 16; ++i) s0[i] = __builtin_amdgcn_exp2f(s0[i]);

        const bool first = (kb == tb0);
        if (first || !__all(mx <= 8.f)) {  // rare fixup (forced on first)
          const float delta = first ? mx : fmaxf(mx, 0.f);
          const float scq = __builtin_amdgcn_exp2f(-delta);
          mrun += delta;
          lsum *= scq;
          float sc[16];
#pragma unroll
          for (int r = 0; r < 16; ++r)
            sc[r] = __shfl(scq, (r & 3) + ((r >> 2) << 3) + hi * 4);
#pragma unroll
          for (int r = 0; r < 16; ++r) { o0[r] *= sc[r]; o1[r] *= sc[r]; }
#pragma unroll
          for (int i = 0; i < 16; ++i) s0[i] *= scq;  // rescale p
        }

        // row-sum: f32 pairwise tree (depth 4); pack pairs to fp16
        const float a0 = (s0[0] + s0[1]) + (s0[2] + s0[3]);
        const float a1 = (s0[4] + s0[5]) + (s0[6] + s0[7]);
        const float a2 = (s0[8] + s0[9]) + (s0[10] + s0[11]);
        const float a3 = (s0[12] + s0[13]) + (s0[14] + s0[15]);
        float ps = (a0 + a1) + (a2 + a3);
        ps += __shfl_xor(ps, 32);  // combine disjoint key halves of hi pair
        lsum += ps;
        unsigned W[8];
#pragma unroll
        for (int u = 0; u < 4; ++u) {
          W[2 * u] = pk2u(s0[4 * u + 0], s0[4 * u + 1]);
          W[2 * u + 1] = pk2u(s0[4 * u + 2], s0[4 * u + 3]);
        }

        // --- PV: assemble P A-frags in registers (lane<->lane^32) ---
        __builtin_amdgcn_s_setprio(1);
#pragma unroll
        for (int ks = 0; ks < 2; ++ks) {
          const unsigned w0 = W[4 * ks + 0], w1 = W[4 * ks + 1];
          const unsigned w2 = W[4 * ks + 2], w3 = W[4 * ks + 3];
          const unsigned sendA = hi ? w0 : w2;
          const unsigned sendB = hi ? w1 : w3;
          const unsigned recvA = __shfl_xor(sendA, 32);
          const unsigned recvB = __shfl_xor(sendB, 32);
          union { unsigned u[4]; f16x8 v; } af;
          af.u[0] = hi ? recvA : w0;
          af.u[1] = hi ? recvB : w1;
          af.u[2] = hi ? w2 : recvA;
          af.u[3] = hi ? w3 : recvB;
          const int g0 = ks * 2 + hi;
          const f16x8 v0f = *(const f16x8*)(Vb + lq * 128 + ((g0 << 4) ^ rsw));
          const f16x8 v1f =
              *(const f16x8*)(Vb + lq * 128 + (((g0 + 4) << 4) ^ rsw));
          o0 = mfma32(af.v, v0f, o0);
          o1 = mfma32(af.v, v1f, o1);
        }
        __builtin_amdgcn_s_setprio(0);
      }
    }

    asm volatile("" ::: "memory");
    __builtin_amdgcn_s_barrier();
  }
#undef STAGE

  // epilogue: normalized partials (o/l, packed fp16 pair d & d+32) + (m,l)
  const size_t rowbase = (size_t)bh * 2048 + q0w;
  const float li = 1.f / lsum;
  unsigned* pod = po + ((size_t)seg * 65536 + rowbase) * 32;
#pragma unroll
  for (int r = 0; r < 16; ++r) {
    const int qr = (r & 3) + ((r >> 2) << 3) + hi * 4;
    const float lr = __shfl(li, qr);
    pod[qr * 32 + lq] = pk2u(o0[r] * lr, o1[r] * lr);
  }
  if (hi == 0) {
    float2 v; v.x = mrun; v.y = lsum;
    ml[(size_t)seg * 65536 + rowbase + lq] = v;
  }
}

// ------------------------------ combine ------------------------------------
// ctx[row][d] = sum_s f_s * ohat_s[row][d], f_s = l_s*2^(m_s-m) / sum(...).
__global__ __launch_bounds__(256) void combine_kernel(
    const unsigned* __restrict__ po, const float2* __restrict__ ml,
    _Float16* __restrict__ ctx) {
  const int tid = blockIdx.x * 256 + threadIdx.x;  // 2097152
  const int row = tid >> 5, dg = tid & 31;
  const float2 a0 = ml[row];
  const float2 a1 = ml[65536 + row];
  const float2 a2 = ml[131072 + row];
  const float2 a3 = ml[196608 + row];
  const float m = fmaxf(fmaxf(a0.x, a1.x), fmaxf(a2.x, a3.x));
  const float w0 = a0.y * __builtin_amdgcn_exp2f(a0.x - m);
  const float w1 = a1.y * __builtin_amdgcn_exp2f(a1.x - m);
  const float w2 = a2.y * __builtin_amdgcn_exp2f(a2.x - m);
  const float w3 = a3.y * __builtin_amdgcn_exp2f(a3.x - m);
  const float inv = 1.f / (w0 + w1 + w2 + w3);
  float acc0 = 0.f, acc1 = 0.f;
  const float f[4] = {w0 * inv, w1 * inv, w2 * inv, w3 * inv};
#pragma unroll
  for (int s = 0; s < 4; ++s) {
    union { unsigned u; fp16x2 h; } x;
    x.u = po[((size_t)s * 65536 + row) * 32 + dg];
    acc0 += f[s] * (float)x.h[0];
    acc1 += f[s] * (float)x.h[1];
  }
  const int bh = row >> 11, n = row & 2047, b = bh >> 4, h = bh & 15;
  _Float16* dst = ctx + ((size_t)(b * 2048 + n) * 1024 + h * 64);
  dst[dg] = (_Float16)acc0;
  dst[dg + 32] = (_Float16)acc1;
}

// ------------------------------ launcher -----------------------------------

extern "C" void kernel_launch(void* const* d_in, const int* in_sizes, int n_in,
                              void* d_out, int out_size, void* d_ws, size_t ws_size,
                              hipStream_t stream) {
  const float* x = (const float*)d_in[0];
  const float* rc = (const float*)d_in[1];
  const float* rs = (const float*)d_in[2];
  const int* lens = (const int*)d_in[3];
  const float* Wq = (const float*)d_in[4];
  const float* bq = (const float*)d_in[5];
  const float* Wk = (const float*)d_in[6];
  const float* bk = (const float*)d_in[7];
  const float* Wv = (const float*)d_in[8];
  const float* bv = (const float*)d_in[9];
  const float* Wo = (const float*)d_in[10];
  const float* bo = (const float*)d_in[11];
  float* out = (float*)d_out;

  char* ws = (char*)d_ws;
  const size_t MB = 1024 * 1024;
  _Float16* XH = (_Float16*)(ws + 0);        // [4096][1024]          8 MB
  _Float16* WT = (_Float16*)(ws + 8 * MB);   // [4][1024 j][1024 k]   8 MB
  _Float16* QK = (_Float16*)(ws + 16 * MB);  // [2][2][16][2048][64] 16 MB
  _Float16* VT = (_Float16*)(ws + 32 * MB);  // [2][16][64][2048]     8 MB
  _Float16* CTX = (_Float16*)(ws + 40 * MB); // [4096][1024]          8 MB
  unsigned* PO = (unsigned*)(ws + 48 * MB);  // [4][65536][32] u32   32 MB
  float2* ML = (float2*)(ws + 80 * MB);      // [4][65536] float2     2 MB
  float* RC2 = (float*)(ws + 48 * MB);       // overlap PO (dead before attn)
  float* RS2 = (float*)(ws + 48 * MB + 512 * 1024);

  prep_kernel<<<dim3(32, 32, 6), dim3(32, 8), 0, stream>>>(
      x, Wq, Wk, Wv, Wo, rc, rs, XH, WT, RC2, RS2);
  gemm_kernel<128, 0><<<768, 256, 0, stream>>>(
      XH, WT, bq, bk, bv, RC2, RS2, nullptr, QK, VT, nullptr);
  attn_kernel<<<2048, 256, 0, stream>>>(QK, VT, lens, PO, ML);
  combine_kernel<<<8192, 256, 0, stream>>>(PO, ML, CTX);
  gemm_kernel<64, 2><<<512, 256, 0, stream>>>(
      CTX, WT + (size_t)3 * 1024 * 1024, bo, nullptr, nullptr, nullptr,
      nullptr, lens, nullptr, nullptr, out);
}

// Round 14
// 152.768 us; speedup vs baseline: 1.0050x; 1.0050x over previous
//
#include <hip/hip_runtime.h>
#include <hip/hip_bf16.h>

// ---------------------------------------------------------------------------
// Attention (B=2,N=2048,D=1024,H=16,DH=64) on gfx950 — full-fp16 pipeline.
//   1. prep: x -> fp16; Wq|Wk|Wv|Wo -> W^T fp16; compact rope tables
//      RC2/RS2 [2048][64] f32 (L2-resident).
//   2. gemm<128,0>: q|k|v = x@W+b in ONE gemm (bijective XCD swizzle);
//      epilogue: rope (+log2e on q) -> QK fp16 via WAVE-PRIVATE LDS
//      TURNAROUND (r14): 64 scalar 2B stores/thread -> 8 coalesced 16B
//      stores/thread (2KB contiguous per wave); v -> VT fp16 (packed 8B).
//   3. attn: flash attn, 32x32x16 MFMA, 4-way key split, 4-wave blocks,
//      2048 blocks, 64-key super-tiles (2x32 chunks per barrier).
//      Round-12 softmax (defer-max, shifted domain, fdot2 row-sum) —
//      round-13 reorder was neutral and cost absmax margin.
//      launch_bounds (256,4) — (256,8) caused the round-9 spill regression.
//   4. combine: weighted-merge 4 segments -> ctx fp16.
//   5. gemm<64,2>: out = (ctx@Wo + bo) * query_mask, f32.
// ---------------------------------------------------------------------------

typedef __fp16 fp16x2 __attribute__((ext_vector_type(2)));
typedef _Float16 f16x8 __attribute__((ext_vector_type(8)));
typedef float f32x4 __attribute__((ext_vector_type(4)));
typedef float f32x16 __attribute__((ext_vector_type(16)));

#define NEGBIG (-1.0e9f)

__device__ inline f32x4 mfma16(f16x8 a, f16x8 b, f32x4 c) {
  return __builtin_amdgcn_mfma_f32_16x16x32_f16(a, b, c, 0, 0, 0);
}
__device__ inline f32x16 mfma32(f16x8 a, f16x8 b, f32x16 c) {
  return __builtin_amdgcn_mfma_f32_32x32x16_f16(a, b, c, 0, 0, 0);
}

__device__ inline void gload16(const void* g, void* l) {
  __builtin_amdgcn_global_load_lds(
      (const __attribute__((address_space(1))) void*)g,
      (__attribute__((address_space(3))) void*)l, 16, 0, 0);
}

__device__ inline unsigned pk2u(float a, float b) {
  union { fp16x2 h; unsigned u; } x;
  x.h = __builtin_amdgcn_cvt_pkrtz(a, b);
  return x.u;
}

__device__ inline float max3f(float a, float b, float c) {
  float d;
  asm("v_max3_f32 %0, %1, %2, %3" : "=v"(d) : "v"(a), "v"(b), "v"(c));
  return d;
}

// -------------------------------- prep -------------------------------------
// z<4: W[z] transpose -> fp16. z==4: x -> fp16. z==5: compact rope tables.
__global__ __launch_bounds__(256) void prep_kernel(
    const float* __restrict__ x, const float* __restrict__ Wq,
    const float* __restrict__ Wk, const float* __restrict__ Wv,
    const float* __restrict__ Wo, const float* __restrict__ rc,
    const float* __restrict__ rs, _Float16* __restrict__ xh,
    _Float16* __restrict__ wt, float* __restrict__ rc2,
    float* __restrict__ rs2) {
  __shared__ float tile[32][33];
  const int z = blockIdx.z;
  const int tx = threadIdx.x, ty = threadIdx.y;
  if (z == 4) {
    const int bid = blockIdx.y * 32 + blockIdx.x;
    const int t = ty * 32 + tx;
#pragma unroll
    for (int i = 0; i < 4; ++i) {
      const int o = bid * 1024 + i * 256 + t;
      const float4 v = ((const float4*)x)[o];
      union { _Float16 h[4]; short4 s; } u;
      u.h[0] = (_Float16)v.x; u.h[1] = (_Float16)v.y;
      u.h[2] = (_Float16)v.z; u.h[3] = (_Float16)v.w;
      ((short4*)xh)[o] = u.s;
    }
    return;
  }
  if (z == 5) {
    const int bid = blockIdx.y * 32 + blockIdx.x;
    const int idx = bid * 256 + ty * 32 + tx;  // over 2048*64 = 131072
    if (idx < 131072) {
      const int n = idx >> 6, d = idx & 63;
      rc2[idx] = rc[(size_t)n * 1024 + d];
      rs2[idx] = rs[(size_t)n * 1024 + d];
    }
    return;
  }
  const float* W = (z == 0) ? Wq : (z == 1) ? Wk : (z == 2) ? Wv : Wo;
  _Float16* dh = wt + (size_t)z * 1024 * 1024;
  const int j0 = blockIdx.x * 32, k0 = blockIdx.y * 32;
  for (int i = ty; i < 32; i += 8)
    tile[i][tx] = W[(size_t)(k0 + i) * 1024 + j0 + tx];
  __syncthreads();
  for (int i = ty; i < 32; i += 8)
    dh[(size_t)(j0 + i) * 1024 + k0 + tx] = (_Float16)tile[tx][i];
}

// -------------------------------- GEMM -------------------------------------
// 1-D grid, bijective XCD swizzle (nwg % 8 == 0). M = 4096 fixed.
template <int TM, int EPI>
__global__ __launch_bounds__(256) void gemm_kernel(
    const _Float16* __restrict__ A, const _Float16* __restrict__ B,
    const float* __restrict__ bias0, const float* __restrict__ bias1,
    const float* __restrict__ bias2,
    const float* __restrict__ ropeC, const float* __restrict__ ropeS,
    const int* __restrict__ lens,
    _Float16* __restrict__ outQK, _Float16* __restrict__ outVT,
    float* __restrict__ outF) {
  constexpr int MI = TM / 32;
  constexpr int MSHIFT = (TM == 128) ? 5 : 6;  // mtiles = 4096/TM
  __shared__ __align__(16) _Float16 smem[(TM + 128) * 32];
  const int t = threadIdx.x;
  const int w = t >> 6, lane = t & 63;
  const int wr = w >> 1, wc = w & 1;
  const int fr = lane & 15, fg = lane >> 4;
  const int nwg = gridDim.x;
  const int bid = blockIdx.x;
  const int wgid = (bid & 7) * (nwg >> 3) + (bid >> 3);
  const int mtile = wgid & ((1 << MSHIFT) - 1);
  const int ntile = wgid >> MSHIFT;

  const int srow = t >> 2;
  const int skel = (t & 3) << 3;
  const size_t aBase = (size_t)(mtile * TM + srow) * 1024 + skel;
  const size_t bBase = (size_t)(ntile * 128 + srow) * 1024 + skel;
  const int ldst = t * 8;
  _Float16* lA = &smem[0];
  _Float16* lB = &smem[TM * 32];

  f32x4 acc[MI][4];
#pragma unroll
  for (int i = 0; i < MI; ++i)
#pragma unroll
    for (int j = 0; j < 4; ++j) {
      acc[i][j][0] = 0.f; acc[i][j][1] = 0.f; acc[i][j][2] = 0.f; acc[i][j][3] = 0.f;
    }

  for (int k0 = 0; k0 < 1024; k0 += 32) {
    gload16(A + aBase + k0, lA + ldst);
    if constexpr (TM == 128) gload16(A + aBase + k0 + 64 * 1024, lA + ldst + 2048);
    gload16(B + bBase + k0, lB + ldst);
    gload16(B + bBase + k0 + 64 * 1024, lB + ldst + 2048);
    __syncthreads();

    f16x8 af[MI], bf[4];
#pragma unroll
    for (int mi = 0; mi < MI; ++mi)
      af[mi] = *(const f16x8*)&lA[(wr * (TM / 2) + mi * 16 + fr) * 32 + fg * 8];
#pragma unroll
    for (int ni = 0; ni < 4; ++ni)
      bf[ni] = *(const f16x8*)&lB[(wc * 64 + ni * 16 + fr) * 32 + fg * 8];
#pragma unroll
    for (int mi = 0; mi < MI; ++mi)
#pragma unroll
      for (int ni = 0; ni < 4; ++ni)
        acc[mi][ni] = mfma16(af[mi], bf[ni], acc[mi][ni]);
    __syncthreads();
  }

  const int rowbase = mtile * TM + wr * (TM / 2);
  const int colbase = ntile * 128 + wc * 64;

  if constexpr (EPI == 0) {
    const int which = colbase >> 10;  // 0=q 1=k 2=v (wave-uniform)
    if (which < 2) {
      // Coalesced QK write via wave-private LDS turnaround (smem is dead
      // after the loop's trailing barrier). Per mi: stage 16 rows x 64 dd
      // fp16 (row stride 72 halves = 144B, 16B-aligned), read 32B/lane,
      // store 2KB contiguous per wave.
      const float* bias = which ? bias1 : bias0;
      const int hh = (colbase >> 6) & 15;
      const int b = rowbase >> 11;
      const int nbase = rowbase & 2047;
      _Float16* lslab = smem + w * 1152;  // 16 x 72 halves = 2304B per wave
      const char* cslab = (const char*)lslab;
      _Float16* qkbase =
          outQK + (size_t)((which * 2 + b) * 16 + hh) * 2048 * 64;
      const int rrow = lane >> 2;           // readback row 0..15
      const int rqo = (lane & 3) * 32;      // byte offset within row
#pragma unroll
      for (int mi = 0; mi < MI; ++mi) {
#pragma unroll
        for (int ni = 0; ni < 4; ++ni) {
          const int dd = ni * 16 + fr;
          const float bv = bias[hh * 64 + dd];
#pragma unroll
          for (int r = 0; r < 4; ++r) {
            const int n = nbase + mi * 16 + fg * 4 + r;
            float val = acc[mi][ni][r] + bv;
            float part = __shfl_xor(val, 1);
            const int ro = n * 64 + dd;  // compact table
            const float c = ropeC[ro], s = ropeS[ro];
            float rot = (fr & 1) ? (val * c + part * s) : (val * c - part * s);
            if (!which) rot *= 1.44269504f;  // log2e folded into q
            lslab[(fg * 4 + r) * 72 + dd] = (_Float16)rot;
          }
        }
        asm volatile("" ::: "memory");
        const uint4 v0 = *(const uint4*)(cslab + rrow * 144 + rqo);
        const uint4 v1 = *(const uint4*)(cslab + rrow * 144 + rqo + 16);
        _Float16* gdst =
            qkbase + (size_t)(nbase + mi * 16 + rrow) * 64 + (lane & 3) * 16;
        *(uint4*)gdst = v0;
        *(uint4*)(gdst + 8) = v1;
        asm volatile("" ::: "memory");
      }
    } else {
#pragma unroll
      for (int ni = 0; ni < 4; ++ni) {
        const int gcol = colbase + ni * 16 + fr;
        const int jj = gcol & 1023;
        const int hh = jj >> 6, dd = jj & 63;
        const float bv = bias2[jj];
#pragma unroll
        for (int mi = 0; mi < MI; ++mi) {
          const int n0 = rowbase + mi * 16 + fg * 4;
          const int b = n0 >> 11, n = n0 & 2047;
          union { _Float16 h[4]; short4 s4; } u;
#pragma unroll
          for (int r = 0; r < 4; ++r) u.h[r] = (_Float16)(acc[mi][ni][r] + bv);
          *(short4*)(outVT + ((size_t)(b * 16 + hh) * 64 + dd) * 2048 + n) = u.s4;
        }
      }
    }
  } else {
    const int b = rowbase >> 11;
    const int len = lens[b];
#pragma unroll
    for (int ni = 0; ni < 4; ++ni) {
      const int gcol = colbase + ni * 16 + fr;
      const float bv = bias0[gcol];
#pragma unroll
      for (int mi = 0; mi < MI; ++mi) {
#pragma unroll
        for (int r = 0; r < 4; ++r) {
          const int m = rowbase + mi * 16 + fg * 4 + r;
          const int n = m & 2047;
          float val = acc[mi][ni][r] + bv;
          if (n >= len) val = 0.f;
          outF[(size_t)m * 1024 + gcol] = val;
        }
      }
    }
  }
}

// ------------------------------ attention ----------------------------------
// 2048 blocks x 4 waves, wave = 32 q rows, 4-way key split. Grid: xcd=gid&7,
// idx=gid>>3; qtile=idx&15, c=(idx>>4)*8+xcd; bh=c>>2, seg=c&3.
// 64-key super-tiles per barrier (2x32-key chunks, shared vmcnt/barrier).
// S^T = mfma32(K,Q): col=lane&31=q (lane-local), row=(r&3)+8*(r>>2)+4*hi=key.
// Shifted-domain softmax: C-init = -mrun, first tile forces rescale.
// LDS: 2 x { K[64][64] 8KB | V 2x4KB } = 32 KiB.
__global__ __launch_bounds__(256, 4) void attn_kernel(
    const _Float16* __restrict__ qk, const _Float16* __restrict__ vt,
    const int* __restrict__ lens, unsigned* __restrict__ po,
    float2* __restrict__ ml) {
  __shared__ __align__(16) char lds[32768];
  const int t = threadIdx.x;
  const int w = t >> 6, lane = t & 63;
  const int lq = lane & 31, hi = lane >> 5;
  const int gid = blockIdx.x;
  const int xcd = gid & 7, idx = gid >> 3;
  const int qtile = idx & 15;
  const int c = ((idx >> 4) << 3) + xcd;  // 0..127, same c -> same XCD
  const int bh = c >> 2, seg = c & 3;
  const int b = bh >> 4, h = bh & 15;
  const int len = lens[b];
  const int q0w = qtile * 128 + w * 32;
  const size_t qoff = (size_t)(b * 16 + h) * 2048 * 64;
  const size_t koff = (size_t)((2 + b) * 16 + h) * 2048 * 64;
  const size_t voff = (size_t)(b * 16 + h) * 64 * 2048;

  // Q B-frags: lane lq = q row, k = ks*16 + hi*8 + j
  f16x8 qf[4];
#pragma unroll
  for (int ks = 0; ks < 4; ++ks)
    qf[ks] = *(const f16x8*)(qk + qoff + (size_t)(q0w + lq) * 64 + ks * 16 + hi * 8);

  // staging (4 issues/thread per 64-key super-tile): linear LDS dest, source
  // pre-swizzled slot ss = (t&7)^(srow&7).
  const int srow = t >> 3;  // 0..31
  const int ss = (t & 7) ^ (srow & 7);
  const size_t kg = koff + (size_t)srow * 64 + ss * 8;
  const int vd = srow + ((ss >> 2) << 5);
  const size_t vg = voff + (size_t)vd * 2048 + (ss & 3) * 8;

  f32x16 o0, o1;
#pragma unroll
  for (int i = 0; i < 16; ++i) { o0[i] = 0.f; o1[i] = 0.f; }
  float mrun = 0.f, lsum = 0.f;  // per-lane, q = lq (replicated on hi pair)

  fp16x2 ones2;
  ones2[0] = (__fp16)1.0f; ones2[1] = (__fp16)1.0f;

#define STAGE(bi, tile0) do { \
    char* dst = lds + (bi) * 16384 + t * 16; \
    const size_t kk = (size_t)(tile0) * 2048; /* tile0*32*64 */ \
    gload16(qk + kg + kk, dst); \
    gload16(qk + kg + kk + 2048, dst + 4096); \
    gload16(vt + vg + (tile0) * 32, dst + 8192); \
    gload16(vt + vg + (tile0) * 32 + 32, dst + 12288); \
  } while (0)

  const int nkb = (len + 31) >> 5;
  const int tb0 = (nkb * seg) >> 2;
  const int tb1 = (nkb * (seg + 1)) >> 2;
  const int nst = (tb1 - tb0 + 1) >> 1;  // 64-key super-tiles

  STAGE(0, tb0);

  for (int st = 0; st < nst; ++st) {
    const int cur = st & 1;
    if (st + 1 < nst) {
      STAGE(cur ^ 1, tb0 + (st + 1) * 2);
      asm volatile("s_waitcnt vmcnt(4)" ::: "memory");
    } else {
      asm volatile("s_waitcnt vmcnt(0)" ::: "memory");
    }
    __builtin_amdgcn_s_barrier();

    const char* Bb = lds + cur * 16384;
    const int rsw = (lq & 7) << 4;

#pragma unroll
    for (int ch = 0; ch < 2; ++ch) {
      const int kb = tb0 + st * 2 + ch;
      if (kb < tb1) {
        const char* Kb = Bb + ch * 4096;
        const char* Vb = Bb + 8192 + ch * 4096;

        // QK^T in shifted domain: C-init = -mrun
        f32x16 s0;
        const float nm = -mrun;
#pragma unroll
        for (int i = 0; i < 16; ++i) s0[i] = nm;
        __builtin_amdgcn_s_setprio(1);
#pragma unroll
        for (int ks = 0; ks < 4; ++ks) {
          const f16x8 kf =
              *(const f16x8*)(Kb + lq * 128 + ((ks * 32 + hi * 16) ^ rsw));
          s0 = mfma32(kf, qf[ks], s0);
        }
        __builtin_amdgcn_s_setprio(0);

        if (kb == nkb - 1 && (len & 31)) {
#pragma unroll
          for (int r = 0; r < 16; ++r) {
            const int key = kb * 32 + (r & 3) + ((r >> 2) << 3) + hi * 4;
            if (key >= len) s0[r] = NEGBIG;
          }
        }

        // --- max reduce (v_max3), q lane-local, shifted domain ---
        const float m0 = max3f(s0[0], s0[1], s0[2]);
        const float m1 = max3f(s0[3], s0[4], s0[5]);
        const float m2 = max3f(s0[6], s0[7], s0[8]);
        const float m3 = max3f(s0[9], s0[10], s0[11]);
        const float m4 = max3f(s0[12], s0[13], s0[14]);
        float mx = fmaxf(max3f(m0, m1, m2), max3f(m3, m4, s0[15]));
        mx = fmaxf(mx, __shfl_xor(mx, 32));

        const bool first = (kb == tb0);
        if (first || !__all(mx <= 8.f)) {  // defer-max; forced on first tile
          const float delta = first ? mx : fmaxf(mx, 0.f);
          const float scq = __builtin_amdgcn_exp2f(-delta);
          mrun += delta;
          lsum *= scq;
          float sc[16];
#pragma unroll
          for (int r = 0; r < 16; ++r)
            sc[r] = __shfl(scq, (r & 3) + ((r >> 2) << 3) + hi * 4);
#pragma unroll
          for (int r = 0; r < 16; ++r) { o0[r] *= sc[r]; o1[r] *= sc[r]; }
#pragma unroll
          for (int i = 0; i < 16; ++i) s0[i] -= delta;
        }

        // p = exp2(s0); pack pairs; row-sum via v_dot2_f32_f16
        unsigned W[8];
#pragma unroll
        for (int u = 0; u < 4; ++u) {
          const float p0 = __builtin_amdgcn_exp2f(s0[4 * u + 0]);
          const float p1 = __builtin_amdgcn_exp2f(s0[4 * u + 1]);
          const float p2 = __builtin_amdgcn_exp2f(s0[4 * u + 2]);
          const float p3 = __builtin_amdgcn_exp2f(s0[4 * u + 3]);
          W[2 * u] = pk2u(p0, p1);
          W[2 * u + 1] = pk2u(p2, p3);
        }
        float ps = 0.f;
#pragma unroll
        for (int i = 0; i < 8; ++i) {
          union { unsigned u; fp16x2 h; } x; x.u = W[i];
          ps = __builtin_amdgcn_fdot2(x.h, ones2, ps, false);
        }
        ps += __shfl_xor(ps, 32);  // combine disjoint key halves of hi pair
        lsum += ps;

        // --- PV: assemble P A-frags in registers (lane<->lane^32) ---
        __builtin_amdgcn_s_setprio(1);
#pragma unroll
        for (int ks = 0; ks < 2; ++ks) {
          const unsigned w0 = W[4 * ks + 0], w1 = W[4 * ks + 1];
          const unsigned w2 = W[4 * ks + 2], w3 = W[4 * ks + 3];
          const unsigned sendA = hi ? w0 : w2;
          const unsigned sendB = hi ? w1 : w3;
          const unsigned recvA = __shfl_xor(sendA, 32);
          const unsigned recvB = __shfl_xor(sendB, 32);
          union { unsigned u[4]; f16x8 v; } af;
          af.u[0] = hi ? recvA : w0;
          af.u[1] = hi ? recvB : w1;
          af.u[2] = hi ? w2 : recvA;
          af.u[3] = hi ? w3 : recvB;
          const int g0 = ks * 2 + hi;
          const f16x8 v0f = *(const f16x8*)(Vb + lq * 128 + ((g0 << 4) ^ rsw));
          const f16x8 v1f =
              *(const f16x8*)(Vb + lq * 128 + (((g0 + 4) << 4) ^ rsw));
          o0 = mfma32(af.v, v0f, o0);
          o1 = mfma32(af.v, v1f, o1);
        }
        __builtin_amdgcn_s_setprio(0);
      }
    }

    asm volatile("" ::: "memory");
    __builtin_amdgcn_s_barrier();
  }
#undef STAGE

  // epilogue: normalized partials (o/l, packed fp16 pair d & d+32) + (m,l)
  const size_t rowbase = (size_t)bh * 2048 + q0w;
  const float li = 1.f / lsum;
  unsigned* pod = po + ((size_t)seg * 65536 + rowbase) * 32;
#pragma unroll
  for (int r = 0; r < 16; ++r) {
    const int qr = (r & 3) + ((r >> 2) << 3) + hi * 4;
    const float lr = __shfl(li, qr);
    pod[qr * 32 + lq] = pk2u(o0[r] * lr, o1[r] * lr);
  }
  if (hi == 0) {
    float2 v; v.x = mrun; v.y = lsum;
    ml[(size_t)seg * 65536 + rowbase + lq] = v;
  }
}

// ------------------------------ combine ------------------------------------
// ctx[row][d] = sum_s f_s * ohat_s[row][d], f_s = l_s*2^(m_s-m) / sum(...).
__global__ __launch_bounds__(256) void combine_kernel(
    const unsigned* __restrict__ po, const float2* __restrict__ ml,
    _Float16* __restrict__ ctx) {
  const int tid = blockIdx.x * 256 + threadIdx.x;  // 2097152
  const int row = tid >> 5, dg = tid & 31;
  const float2 a0 = ml[row];
  const float2 a1 = ml[65536 + row];
  const float2 a2 = ml[131072 + row];
  const float2 a3 = ml[196608 + row];
  const float m = fmaxf(fmaxf(a0.x, a1.x), fmaxf(a2.x, a3.x));
  const float w0 = a0.y * __builtin_amdgcn_exp2f(a0.x - m);
  const float w1 = a1.y * __builtin_amdgcn_exp2f(a1.x - m);
  const float w2 = a2.y * __builtin_amdgcn_exp2f(a2.x - m);
  const float w3 = a3.y * __builtin_amdgcn_exp2f(a3.x - m);
  const float inv = 1.f / (w0 + w1 + w2 + w3);
  float acc0 = 0.f, acc1 = 0.f;
  const float f[4] = {w0 * inv, w1 * inv, w2 * inv, w3 * inv};
#pragma unroll
  for (int s = 0; s < 4; ++s) {
    union { unsigned u; fp16x2 h; } x;
    x.u = po[((size_t)s * 65536 + row) * 32 + dg];
    acc0 += f[s] * (float)x.h[0];
    acc1 += f[s] * (float)x.h[1];
  }
  const int bh = row >> 11, n = row & 2047, b = bh >> 4, h = bh & 15;
  _Float16* dst = ctx + ((size_t)(b * 2048 + n) * 1024 + h * 64);
  dst[dg] = (_Float16)acc0;
  dst[dg + 32] = (_Float16)acc1;
}

// ------------------------------ launcher -----------------------------------

extern "C" void kernel_launch(void* const* d_in, const int* in_sizes, int n_in,
                              void* d_out, int out_size, void* d_ws, size_t ws_size,
                              hipStream_t stream) {
  const float* x = (const float*)d_in[0];
  const float* rc = (const float*)d_in[1];
  const float* rs = (const float*)d_in[2];
  const int* lens = (const int*)d_in[3];
  const float* Wq = (const float*)d_in[4];
  const float* bq = (const float*)d_in[5];
  const float* Wk = (const float*)d_in[6];
  const float* bk = (const float*)d_in[7];
  const float* Wv = (const float*)d_in[8];
  const float* bv = (const float*)d_in[9];
  const float* Wo = (const float*)d_in[10];
  const float* bo = (const float*)d_in[11];
  float* out = (float*)d_out;

  char* ws = (char*)d_ws;
  const size_t MB = 1024 * 1024;
  _Float16* XH = (_Float16*)(ws + 0);        // [4096][1024]          8 MB
  _Float16* WT = (_Float16*)(ws + 8 * MB);   // [4][1024 j][1024 k]   8 MB
  _Float16* QK = (_Float16*)(ws + 16 * MB);  // [2][2][16][2048][64] 16 MB
  _Float16* VT = (_Float16*)(ws + 32 * MB);  // [2][16][64][2048]     8 MB
  _Float16* CTX = (_Float16*)(ws + 40 * MB); // [4096][1024]          8 MB
  unsigned* PO = (unsigned*)(ws + 48 * MB);  // [4][65536][32] u32   32 MB
  float2* ML = (float2*)(ws + 80 * MB);      // [4][65536] float2     2 MB
  float* RC2 = (float*)(ws + 48 * MB);       // overlap PO (dead before attn)
  float* RS2 = (float*)(ws + 48 * MB + 512 * 1024);

  prep_kernel<<<dim3(32, 32, 6), dim3(32, 8), 0, stream>>>(
      x, Wq, Wk, Wv, Wo, rc, rs, XH, WT, RC2, RS2);
  gemm_kernel<128, 0><<<768, 256, 0, stream>>>(
      XH, WT, bq, bk, bv, RC2, RS2, nullptr, QK, VT, nullptr);
  attn_kernel<<<2048, 256, 0, stream>>>(QK, VT, lens, PO, ML);
  combine_kernel<<<8192, 256, 0, stream>>>(PO, ML, CTX);
  gemm_kernel<64, 2><<<512, 256, 0, stream>>>(
      CTX, WT + (size_t)3 * 1024 * 1024, bo, nullptr, nullptr, nullptr,
      nullptr, lens, nullptr, nullptr, out);
}

// Round 15
// 138.235 us; speedup vs baseline: 1.1107x; 1.1051x over previous
//
#include <hip/hip_runtime.h>
#include <hip/hip_bf16.h>

// ---------------------------------------------------------------------------
// Attention (B=2,N=2048,D=1024,H=16,DH=64) on gfx950 — full-fp16 pipeline.
//   1. prep: x -> fp16; W^T fp16; compact rope tables RC2/RS2 [2048][64].
//   2. gemm256 (r15): q|k|v = x@W+b, 256x256 tile, BK=64, 8 waves, 128KB
//      dbuf LDS, counted vmcnt(8) (attn-proven STAGE pattern) — halves
//      staging traffic (384->192MB) vs 128² and removes the vmcnt(0) drain.
//      Epilogue: rope (+log2e on q) via wave-private LDS turnaround -> QK;
//      v -> VT [B,H,64,N] (packed 8B).
//   3. attn: flash attn, 32x32x16 MFMA, 4-way key split, 4-wave blocks,
//      2048 blocks, 64-key super-tiles; round-12 softmax. (256,4) bounds —
//      (256,8) caused the round-9 spill regression.
//   4. combine: weighted-merge 4 segments -> ctx fp16.
//   5. gemm<64,2>: out = (ctx@Wo + bo) * query_mask, f32 (old kernel).
// ---------------------------------------------------------------------------

typedef __fp16 fp16x2 __attribute__((ext_vector_type(2)));
typedef _Float16 f16x8 __attribute__((ext_vector_type(8)));
typedef float f32x4 __attribute__((ext_vector_type(4)));
typedef float f32x16 __attribute__((ext_vector_type(16)));

#define NEGBIG (-1.0e9f)

__device__ inline f32x4 mfma16(f16x8 a, f16x8 b, f32x4 c) {
  return __builtin_amdgcn_mfma_f32_16x16x32_f16(a, b, c, 0, 0, 0);
}
__device__ inline f32x16 mfma32(f16x8 a, f16x8 b, f32x16 c) {
  return __builtin_amdgcn_mfma_f32_32x32x16_f16(a, b, c, 0, 0, 0);
}

__device__ inline void gload16(const void* g, void* l) {
  __builtin_amdgcn_global_load_lds(
      (const __attribute__((address_space(1))) void*)g,
      (__attribute__((address_space(3))) void*)l, 16, 0, 0);
}

__device__ inline unsigned pk2u(float a, float b) {
  union { fp16x2 h; unsigned u; } x;
  x.h = __builtin_amdgcn_cvt_pkrtz(a, b);
  return x.u;
}

__device__ inline float max3f(float a, float b, float c) {
  float d;
  asm("v_max3_f32 %0, %1, %2, %3" : "=v"(d) : "v"(a), "v"(b), "v"(c));
  return d;
}

// -------------------------------- prep -------------------------------------
__global__ __launch_bounds__(256) void prep_kernel(
    const float* __restrict__ x, const float* __restrict__ Wq,
    const float* __restrict__ Wk, const float* __restrict__ Wv,
    const float* __restrict__ Wo, const float* __restrict__ rc,
    const float* __restrict__ rs, _Float16* __restrict__ xh,
    _Float16* __restrict__ wt, float* __restrict__ rc2,
    float* __restrict__ rs2) {
  __shared__ float tile[32][33];
  const int z = blockIdx.z;
  const int tx = threadIdx.x, ty = threadIdx.y;
  if (z == 4) {
    const int bid = blockIdx.y * 32 + blockIdx.x;
    const int t = ty * 32 + tx;
#pragma unroll
    for (int i = 0; i < 4; ++i) {
      const int o = bid * 1024 + i * 256 + t;
      const float4 v = ((const float4*)x)[o];
      union { _Float16 h[4]; short4 s; } u;
      u.h[0] = (_Float16)v.x; u.h[1] = (_Float16)v.y;
      u.h[2] = (_Float16)v.z; u.h[3] = (_Float16)v.w;
      ((short4*)xh)[o] = u.s;
    }
    return;
  }
  if (z == 5) {
    const int bid = blockIdx.y * 32 + blockIdx.x;
    const int idx = bid * 256 + ty * 32 + tx;  // over 2048*64 = 131072
    if (idx < 131072) {
      const int n = idx >> 6, d = idx & 63;
      rc2[idx] = rc[(size_t)n * 1024 + d];
      rs2[idx] = rs[(size_t)n * 1024 + d];
    }
    return;
  }
  const float* W = (z == 0) ? Wq : (z == 1) ? Wk : (z == 2) ? Wv : Wo;
  _Float16* dh = wt + (size_t)z * 1024 * 1024;
  const int j0 = blockIdx.x * 32, k0 = blockIdx.y * 32;
  for (int i = ty; i < 32; i += 8)
    tile[i][tx] = W[(size_t)(k0 + i) * 1024 + j0 + tx];
  __syncthreads();
  for (int i = ty; i < 32; i += 8)
    dh[(size_t)(j0 + i) * 1024 + k0 + tx] = (_Float16)tile[tx][i];
}

// ---------------------- QKV GEMM: 256x256, 8 waves -------------------------
// C[m][j] = sum_k A[m][k]*B[j][k]; M=4096, N=3072, K=1024. BK=64, 16 K-tiles,
// double-buffered 128KB LDS, counted vmcnt(8) (attn STAGE pattern).
// Staging: 8-slot XOR swizzle via pre-swizzled source, linear LDS dest.
// Wave (wr=w>>2, wc=w&3) owns rows wr*128+[0,128), cols wc*64+[0,64).
// Grid 192 blocks (mtiles 16 x ntiles 12), bijective XCD swizzle.
__global__ __launch_bounds__(512) void gemm256_kernel(
    const _Float16* __restrict__ A, const _Float16* __restrict__ B,
    const float* __restrict__ bias0, const float* __restrict__ bias1,
    const float* __restrict__ bias2, const float* __restrict__ ropeC,
    const float* __restrict__ ropeS, _Float16* __restrict__ outQK,
    _Float16* __restrict__ outVT) {
  __shared__ __align__(16) char lds[131072];
  const int t = threadIdx.x;
  const int lane = t & 63, w = t >> 6;
  const int wr = w >> 2, wc = w & 3;
  const int fr = lane & 15, fg = lane >> 4;
  const int bid = blockIdx.x;
  const int wgid = (bid & 7) * 24 + (bid >> 3);  // 192 % 8 == 0, bijective
  const int mtile = wgid & 15, ntile = wgid >> 4;

  // staging: thread covers row srw (+64 per issue), slot ss (pre-swizzled)
  const int srw = t >> 3;                       // 0..63
  const int ss8 = (((t & 7) ^ (srw & 7)) << 3); // fp16 elems
  const size_t aRow = (size_t)(mtile * 256 + srw) * 1024 + ss8;
  const size_t bRow = (size_t)(ntile * 256 + srw) * 1024 + ss8;
  const int t16 = t * 16;

  f32x4 acc[8][4];
#pragma unroll
  for (int i = 0; i < 8; ++i)
#pragma unroll
    for (int j = 0; j < 4; ++j) {
      acc[i][j][0] = 0.f; acc[i][j][1] = 0.f; acc[i][j][2] = 0.f; acc[i][j][3] = 0.f;
    }

#define G256(c, kt_) do { \
    const size_t kc = (size_t)(kt_) * 64; \
    char* ab = lds + (c) * 32768 + t16; \
    char* bb = lds + 65536 + (c) * 32768 + t16; \
    gload16(A + aRow + kc, ab); \
    gload16(A + aRow + kc + 65536, ab + 8192); \
    gload16(A + aRow + kc + 131072, ab + 16384); \
    gload16(A + aRow + kc + 196608, ab + 24576); \
    gload16(B + bRow + kc, bb); \
    gload16(B + bRow + kc + 65536, bb + 8192); \
    gload16(B + bRow + kc + 131072, bb + 16384); \
    gload16(B + bRow + kc + 196608, bb + 24576); \
  } while (0)

  G256(0, 0);
  for (int kt = 0; kt < 16; ++kt) {
    const int cur = kt & 1;
    if (kt < 15) {
      G256(cur ^ 1, kt + 1);
      asm volatile("s_waitcnt vmcnt(8)" ::: "memory");
    } else {
      asm volatile("s_waitcnt vmcnt(0)" ::: "memory");
    }
    __builtin_amdgcn_s_barrier();

    const char* La = lds + cur * 32768;
    const char* Lb = lds + 65536 + cur * 32768;
    const int swz = (fr & 7) << 4;
#pragma unroll
    for (int kk = 0; kk < 2; ++kk) {
      const int ko = (kk * 64 + fg * 16) ^ swz;
      f16x8 af[8], bf[4];
#pragma unroll
      for (int mi = 0; mi < 8; ++mi)
        af[mi] = *(const f16x8*)(La + (wr * 128 + mi * 16 + fr) * 128 + ko);
#pragma unroll
      for (int ni = 0; ni < 4; ++ni)
        bf[ni] = *(const f16x8*)(Lb + (wc * 64 + ni * 16 + fr) * 128 + ko);
      __builtin_amdgcn_s_setprio(1);
#pragma unroll
      for (int mi = 0; mi < 8; ++mi)
#pragma unroll
        for (int ni = 0; ni < 4; ++ni)
          acc[mi][ni] = mfma16(af[mi], bf[ni], acc[mi][ni]);
      __builtin_amdgcn_s_setprio(0);
    }
    asm volatile("" ::: "memory");
    __builtin_amdgcn_s_barrier();
  }
#undef G256

  const int rowbase = mtile * 256 + wr * 128;
  const int colbase = ntile * 256 + wc * 64;
  const int which = colbase >> 10;  // 0=q 1=k 2=v (wave-uniform, 64-aligned)

  if (which < 2) {
    // rope + wave-private LDS turnaround -> coalesced 2KB/wave stores
    const float* bias = which ? bias1 : bias0;
    const int hh = (colbase >> 6) & 15;
    const int b = rowbase >> 11;
    const int nbase = rowbase & 2047;
    _Float16* lslab = (_Float16*)lds + w * 1152;  // 16 x 72 halves per wave
    const char* cslab = (const char*)lslab;
    _Float16* qkbase = outQK + (size_t)((which * 2 + b) * 16 + hh) * 2048 * 64;
    const int rrow = lane >> 2;
    const int rqo = (lane & 3) * 32;
#pragma unroll
    for (int mi = 0; mi < 8; ++mi) {
#pragma unroll
      for (int ni = 0; ni < 4; ++ni) {
        const int dd = ni * 16 + fr;
        const float bv = bias[hh * 64 + dd];
#pragma unroll
        for (int r = 0; r < 4; ++r) {
          const int n = nbase + mi * 16 + fg * 4 + r;
          float val = acc[mi][ni][r] + bv;
          float part = __shfl_xor(val, 1);
          const int ro = n * 64 + dd;  // compact table
          const float c = ropeC[ro], s = ropeS[ro];
          float rot = (fr & 1) ? (val * c + part * s) : (val * c - part * s);
          if (!which) rot *= 1.44269504f;  // log2e folded into q
          lslab[(fg * 4 + r) * 72 + dd] = (_Float16)rot;
        }
      }
      asm volatile("" ::: "memory");
      const uint4 v0 = *(const uint4*)(cslab + rrow * 144 + rqo);
      const uint4 v1 = *(const uint4*)(cslab + rrow * 144 + rqo + 16);
      _Float16* gdst =
          qkbase + (size_t)(nbase + mi * 16 + rrow) * 64 + (lane & 3) * 16;
      *(uint4*)gdst = v0;
      *(uint4*)(gdst + 8) = v1;
      asm volatile("" ::: "memory");
    }
  } else {
#pragma unroll
    for (int ni = 0; ni < 4; ++ni) {
      const int gcol = colbase + ni * 16 + fr;
      const int jj = gcol & 1023;
      const int hh = jj >> 6, dd = jj & 63;
      const float bv = bias2[jj];
#pragma unroll
      for (int mi = 0; mi < 8; ++mi) {
        const int n0 = rowbase + mi * 16 + fg * 4;
        const int b = n0 >> 11, n = n0 & 2047;
        union { _Float16 h[4]; short4 s4; } u;
#pragma unroll
        for (int r = 0; r < 4; ++r) u.h[r] = (_Float16)(acc[mi][ni][r] + bv);
        *(short4*)(outVT + ((size_t)(b * 16 + hh) * 64 + dd) * 2048 + n) = u.s4;
      }
    }
  }
}

// ---------------------- OUT GEMM (old 128-col kernel) ----------------------
template <int TM, int EPI>
__global__ __launch_bounds__(256) void gemm_kernel(
    const _Float16* __restrict__ A, const _Float16* __restrict__ B,
    const float* __restrict__ bias0, const int* __restrict__ lens,
    float* __restrict__ outF) {
  constexpr int MI = TM / 32;
  constexpr int MSHIFT = (TM == 128) ? 5 : 6;
  __shared__ __align__(16) _Float16 smem[(TM + 128) * 32];
  const int t = threadIdx.x;
  const int w = t >> 6, lane = t & 63;
  const int wr = w >> 1, wc = w & 1;
  const int fr = lane & 15, fg = lane >> 4;
  const int nwg = gridDim.x;
  const int bid = blockIdx.x;
  const int wgid = (bid & 7) * (nwg >> 3) + (bid >> 3);
  const int mtile = wgid & ((1 << MSHIFT) - 1);
  const int ntile = wgid >> MSHIFT;

  const int srow = t >> 2;
  const int skel = (t & 3) << 3;
  const size_t aBase = (size_t)(mtile * TM + srow) * 1024 + skel;
  const size_t bBase = (size_t)(ntile * 128 + srow) * 1024 + skel;
  const int ldst = t * 8;
  _Float16* lA = &smem[0];
  _Float16* lB = &smem[TM * 32];

  f32x4 acc[MI][4];
#pragma unroll
  for (int i = 0; i < MI; ++i)
#pragma unroll
    for (int j = 0; j < 4; ++j) {
      acc[i][j][0] = 0.f; acc[i][j][1] = 0.f; acc[i][j][2] = 0.f; acc[i][j][3] = 0.f;
    }

  for (int k0 = 0; k0 < 1024; k0 += 32) {
    gload16(A + aBase + k0, lA + ldst);
    if constexpr (TM == 128) gload16(A + aBase + k0 + 64 * 1024, lA + ldst + 2048);
    gload16(B + bBase + k0, lB + ldst);
    gload16(B + bBase + k0 + 64 * 1024, lB + ldst + 2048);
    __syncthreads();

    f16x8 af[MI], bf[4];
#pragma unroll
    for (int mi = 0; mi < MI; ++mi)
      af[mi] = *(const f16x8*)&lA[(wr * (TM / 2) + mi * 16 + fr) * 32 + fg * 8];
#pragma unroll
    for (int ni = 0; ni < 4; ++ni)
      bf[ni] = *(const f16x8*)&lB[(wc * 64 + ni * 16 + fr) * 32 + fg * 8];
#pragma unroll
    for (int mi = 0; mi < MI; ++mi)
#pragma unroll
      for (int ni = 0; ni < 4; ++ni)
        acc[mi][ni] = mfma16(af[mi], bf[ni], acc[mi][ni]);
    __syncthreads();
  }

  const int rowbase = mtile * TM + wr * (TM / 2);
  const int colbase = ntile * 128 + wc * 64;
  const int b = rowbase >> 11;
  const int len = lens[b];
#pragma unroll
  for (int ni = 0; ni < 4; ++ni) {
    const int gcol = colbase + ni * 16 + fr;
    const float bv = bias0[gcol];
#pragma unroll
    for (int mi = 0; mi < MI; ++mi) {
#pragma unroll
      for (int r = 0; r < 4; ++r) {
        const int m = rowbase + mi * 16 + fg * 4 + r;
        const int n = m & 2047;
        float val = acc[mi][ni][r] + bv;
        if (n >= len) val = 0.f;
        outF[(size_t)m * 1024 + gcol] = val;
      }
    }
  }
}

// ------------------------------ attention ----------------------------------
// 2048 blocks x 4 waves, wave = 32 q rows, 4-way key split. Grid: xcd=gid&7,
// idx=gid>>3; qtile=idx&15, c=(idx>>4)*8+xcd; bh=c>>2, seg=c&3.
// 64-key super-tiles per barrier (2x32-key chunks, shared vmcnt/barrier).
// S^T = mfma32(K,Q): col=lane&31=q (lane-local), row=(r&3)+8*(r>>2)+4*hi=key.
// Shifted-domain softmax: C-init = -mrun, first tile forces rescale.
// LDS: 2 x { K[64][64] 8KB | V 2x4KB } = 32 KiB.
__global__ __launch_bounds__(256, 4) void attn_kernel(
    const _Float16* __restrict__ qk, const _Float16* __restrict__ vt,
    const int* __restrict__ lens, unsigned* __restrict__ po,
    float2* __restrict__ ml) {
  __shared__ __align__(16) char lds[32768];
  const int t = threadIdx.x;
  const int w = t >> 6, lane = t & 63;
  const int lq = lane & 31, hi = lane >> 5;
  const int gid = blockIdx.x;
  const int xcd = gid & 7, idx = gid >> 3;
  const int qtile = idx & 15;
  const int c = ((idx >> 4) << 3) + xcd;  // 0..127, same c -> same XCD
  const int bh = c >> 2, seg = c & 3;
  const int b = bh >> 4, h = bh & 15;
  const int len = lens[b];
  const int q0w = qtile * 128 + w * 32;
  const size_t qoff = (size_t)(b * 16 + h) * 2048 * 64;
  const size_t koff = (size_t)((2 + b) * 16 + h) * 2048 * 64;
  const size_t voff = (size_t)(b * 16 + h) * 64 * 2048;

  f16x8 qf[4];
#pragma unroll
  for (int ks = 0; ks < 4; ++ks)
    qf[ks] = *(const f16x8*)(qk + qoff + (size_t)(q0w + lq) * 64 + ks * 16 + hi * 8);

  const int srow = t >> 3;  // 0..31
  const int ss = (t & 7) ^ (srow & 7);
  const size_t kg = koff + (size_t)srow * 64 + ss * 8;
  const int vd = srow + ((ss >> 2) << 5);
  const size_t vg = voff + (size_t)vd * 2048 + (ss & 3) * 8;

  f32x16 o0, o1;
#pragma unroll
  for (int i = 0; i < 16; ++i) { o0[i] = 0.f; o1[i] = 0.f; }
  float mrun = 0.f, lsum = 0.f;

  fp16x2 ones2;
  ones2[0] = (__fp16)1.0f; ones2[1] = (__fp16)1.0f;

#define STAGE(bi, tile0) do { \
    char* dst = lds + (bi) * 16384 + t * 16; \
    const size_t kk = (size_t)(tile0) * 2048; \
    gload16(qk + kg + kk, dst); \
    gload16(qk + kg + kk + 2048, dst + 4096); \
    gload16(vt + vg + (tile0) * 32, dst + 8192); \
    gload16(vt + vg + (tile0) * 32 + 32, dst + 12288); \
  } while (0)

  const int nkb = (len + 31) >> 5;
  const int tb0 = (nkb * seg) >> 2;
  const int tb1 = (nkb * (seg + 1)) >> 2;
  const int nst = (tb1 - tb0 + 1) >> 1;

  STAGE(0, tb0);

  for (int st = 0; st < nst; ++st) {
    const int cur = st & 1;
    if (st + 1 < nst) {
      STAGE(cur ^ 1, tb0 + (st + 1) * 2);
      asm volatile("s_waitcnt vmcnt(4)" ::: "memory");
    } else {
      asm volatile("s_waitcnt vmcnt(0)" ::: "memory");
    }
    __builtin_amdgcn_s_barrier();

    const char* Bb = lds + cur * 16384;
    const int rsw = (lq & 7) << 4;

#pragma unroll
    for (int ch = 0; ch < 2; ++ch) {
      const int kb = tb0 + st * 2 + ch;
      if (kb < tb1) {
        const char* Kb = Bb + ch * 4096;
        const char* Vb = Bb + 8192 + ch * 4096;

        f32x16 s0;
        const float nm = -mrun;
#pragma unroll
        for (int i = 0; i < 16; ++i) s0[i] = nm;
        __builtin_amdgcn_s_setprio(1);
#pragma unroll
        for (int ks = 0; ks < 4; ++ks) {
          const f16x8 kf =
              *(const f16x8*)(Kb + lq * 128 + ((ks * 32 + hi * 16) ^ rsw));
          s0 = mfma32(kf, qf[ks], s0);
        }
        __builtin_amdgcn_s_setprio(0);

        if (kb == nkb - 1 && (len & 31)) {
#pragma unroll
          for (int r = 0; r < 16; ++r) {
            const int key = kb * 32 + (r & 3) + ((r >> 2) << 3) + hi * 4;
            if (key >= len) s0[r] = NEGBIG;
          }
        }

        const float m0 = max3f(s0[0], s0[1], s0[2]);
        const float m1 = max3f(s0[3], s0[4], s0[5]);
        const float m2 = max3f(s0[6], s0[7], s0[8]);
        const float m3 = max3f(s0[9], s0[10], s0[11]);
        const float m4 = max3f(s0[12], s0[13], s0[14]);
        float mx = fmaxf(max3f(m0, m1, m2), max3f(m3, m4, s0[15]));
        mx = fmaxf(mx, __shfl_xor(mx, 32));

        const bool first = (kb == tb0);
        if (first || !__all(mx <= 8.f)) {
          const float delta = first ? mx : fmaxf(mx, 0.f);
          const float scq = __builtin_amdgcn_exp2f(-delta);
          mrun += delta;
          lsum *= scq;
          float sc[16];
#pragma unroll
          for (int r = 0; r < 16; ++r)
            sc[r] = __shfl(scq, (r & 3) + ((r >> 2) << 3) + hi * 4);
#pragma unroll
          for (int r = 0; r < 16; ++r) { o0[r] *= sc[r]; o1[r] *= sc[r]; }
#pragma unroll
          for (int i = 0; i < 16; ++i) s0[i] -= delta;
        }

        unsigned W[8];
#pragma unroll
        for (int u = 0; u < 4; ++u) {
          const float p0 = __builtin_amdgcn_exp2f(s0[4 * u + 0]);
          const float p1 = __builtin_amdgcn_exp2f(s0[4 * u + 1]);
          const float p2 = __builtin_amdgcn_exp2f(s0[4 * u + 2]);
          const float p3 = __builtin_amdgcn_exp2f(s0[4 * u + 3]);
          W[2 * u] = pk2u(p0, p1);
          W[2 * u + 1] = pk2u(p2, p3);
        }
        float ps = 0.f;
#pragma unroll
        for (int i = 0; i < 8; ++i) {
          union { unsigned u; fp16x2 h; } x; x.u = W[i];
          ps = __builtin_amdgcn_fdot2(x.h, ones2, ps, false);
        }
        ps += __shfl_xor(ps, 32);
        lsum += ps;

        __builtin_amdgcn_s_setprio(1);
#pragma unroll
        for (int ks = 0; ks < 2; ++ks) {
          const unsigned w0 = W[4 * ks + 0], w1 = W[4 * ks + 1];
          const unsigned w2 = W[4 * ks + 2], w3 = W[4 * ks + 3];
          const unsigned sendA = hi ? w0 : w2;
          const unsigned sendB = hi ? w1 : w3;
          const unsigned recvA = __shfl_xor(sendA, 32);
          const unsigned recvB = __shfl_xor(sendB, 32);
          union { unsigned u[4]; f16x8 v; } af;
          af.u[0] = hi ? recvA : w0;
          af.u[1] = hi ? recvB : w1;
          af.u[2] = hi ? w2 : recvA;
          af.u[3] = hi ? w3 : recvB;
          const int g0 = ks * 2 + hi;
          const f16x8 v0f = *(const f16x8*)(Vb + lq * 128 + ((g0 << 4) ^ rsw));
          const f16x8 v1f =
              *(const f16x8*)(Vb + lq * 128 + (((g0 + 4) << 4) ^ rsw));
          o0 = mfma32(af.v, v0f, o0);
          o1 = mfma32(af.v, v1f, o1);
        }
        __builtin_amdgcn_s_setprio(0);
      }
    }

    asm volatile("" ::: "memory");
    __builtin_amdgcn_s_barrier();
  }
#undef STAGE

  const size_t rowbase = (size_t)bh * 2048 + q0w;
  const float li = 1.f / lsum;
  unsigned* pod = po + ((size_t)seg * 65536 + rowbase) * 32;
#pragma unroll
  for (int r = 0; r < 16; ++r) {
    const int qr = (r & 3) + ((r >> 2) << 3) + hi * 4;
    const float lr = __shfl(li, qr);
    pod[qr * 32 + lq] = pk2u(o0[r] * lr, o1[r] * lr);
  }
  if (hi == 0) {
    float2 v; v.x = mrun; v.y = lsum;
    ml[(size_t)seg * 65536 + rowbase + lq] = v;
  }
}

// ------------------------------ combine ------------------------------------
__global__ __launch_bounds__(256) void combine_kernel(
    const unsigned* __restrict__ po, const float2* __restrict__ ml,
    _Float16* __restrict__ ctx) {
  const int tid = blockIdx.x * 256 + threadIdx.x;  // 2097152
  const int row = tid >> 5, dg = tid & 31;
  const float2 a0 = ml[row];
  const float2 a1 = ml[65536 + row];
  const float2 a2 = ml[131072 + row];
  const float2 a3 = ml[196608 + row];
  const float m = fmaxf(fmaxf(a0.x, a1.x), fmaxf(a2.x, a3.x));
  const float w0 = a0.y * __builtin_amdgcn_exp2f(a0.x - m);
  const float w1 = a1.y * __builtin_amdgcn_exp2f(a1.x - m);
  const float w2 = a2.y * __builtin_amdgcn_exp2f(a2.x - m);
  const float w3 = a3.y * __builtin_amdgcn_exp2f(a3.x - m);
  const float inv = 1.f / (w0 + w1 + w2 + w3);
  float acc0 = 0.f, acc1 = 0.f;
  const float f[4] = {w0 * inv, w1 * inv, w2 * inv, w3 * inv};
#pragma unroll
  for (int s = 0; s < 4; ++s) {
    union { unsigned u; fp16x2 h; } x;
    x.u = po[((size_t)s * 65536 + row) * 32 + dg];
    acc0 += f[s] * (float)x.h[0];
    acc1 += f[s] * (float)x.h[1];
  }
  const int bh = row >> 11, n = row & 2047, b = bh >> 4, h = bh & 15;
  _Float16* dst = ctx + ((size_t)(b * 2048 + n) * 1024 + h * 64);
  dst[dg] = (_Float16)acc0;
  dst[dg + 32] = (_Float16)acc1;
}

// ------------------------------ launcher -----------------------------------

extern "C" void kernel_launch(void* const* d_in, const int* in_sizes, int n_in,
                              void* d_out, int out_size, void* d_ws, size_t ws_size,
                              hipStream_t stream) {
  const float* x = (const float*)d_in[0];
  const float* rc = (const float*)d_in[1];
  const float* rs = (const float*)d_in[2];
  const int* lens = (const int*)d_in[3];
  const float* Wq = (const float*)d_in[4];
  const float* bq = (const float*)d_in[5];
  const float* Wk = (const float*)d_in[6];
  const float* bk = (const float*)d_in[7];
  const float* Wv = (const float*)d_in[8];
  const float* bv = (const float*)d_in[9];
  const float* Wo = (const float*)d_in[10];
  const float* bo = (const float*)d_in[11];
  float* out = (float*)d_out;

  char* ws = (char*)d_ws;
  const size_t MB = 1024 * 1024;
  _Float16* XH = (_Float16*)(ws + 0);        // [4096][1024]          8 MB
  _Float16* WT = (_Float16*)(ws + 8 * MB);   // [4][1024 j][1024 k]   8 MB
  _Float16* QK = (_Float16*)(ws + 16 * MB);  // [2][2][16][2048][64] 16 MB
  _Float16* VT = (_Float16*)(ws + 32 * MB);  // [2][16][64][2048]     8 MB
  _Float16* CTX = (_Float16*)(ws + 40 * MB); // [4096][1024]          8 MB
  unsigned* PO = (unsigned*)(ws + 48 * MB);  // [4][65536][32] u32   32 MB
  float2* ML = (float2*)(ws + 80 * MB);      // [4][65536] float2     2 MB
  float* RC2 = (float*)(ws + 48 * MB);       // overlap PO (dead before attn)
  float* RS2 = (float*)(ws + 48 * MB + 512 * 1024);

  prep_kernel<<<dim3(32, 32, 6), dim3(32, 8), 0, stream>>>(
      x, Wq, Wk, Wv, Wo, rc, rs, XH, WT, RC2, RS2);
  gemm256_kernel<<<192, 512, 0, stream>>>(XH, WT, bq, bk, bv, RC2, RS2, QK,
                                          VT);
  attn_kernel<<<2048, 256, 0, stream>>>(QK, VT, lens, PO, ML);
  combine_kernel<<<8192, 256, 0, stream>>>(PO, ML, CTX);
  gemm_kernel<64, 2><<<512, 256, 0, stream>>>(
      CTX, WT + (size_t)3 * 1024 * 1024, bo, lens, out);
}